// Round 22
// baseline (1072.143 us; speedup 1.0000x reference)
//
#include <hip/hip_runtime.h>

#define H 128
#define H3 384
#define NPG 16
#define EPG 16
#define GPB 2
#define ROWS (GPB*NPG)      // 32 rows (nodes) per block
#define NSTEPS 12
#define OPS 105

__device__ __forceinline__ float lrelu(float x){ return x > 0.0f ? x : 0.01f*x; }
__device__ __forceinline__ float sigm(float x){ return 1.0f/(1.0f+__expf(-x)); }
__device__ __forceinline__ float tanhx(float x){
  x = fminf(15.f, fmaxf(-15.f, x));
  float e = __expf(2.f*x);
  return (e-1.f)/(e+1.f);
}

__device__ __forceinline__ void fma4(float4& a, float s, const float4& w){
  a.x = fmaf(s, w.x, a.x); a.y = fmaf(s, w.y, a.y);
  a.z = fmaf(s, w.z, a.z); a.w = fmaf(s, w.w, a.w);
}

// pre-transpose gru_wih/gru_whh [384,128] -> [128,384] (k-major) for coalesced matvec loads
__global__ void transpose_k(const float* __restrict__ wih, const float* __restrict__ whh,
                            float* __restrict__ wihT, float* __restrict__ whhT){
  int idx = blockIdx.x * 256 + threadIdx.x;
  if (idx < 3*H*H) {
    int j = idx / H;        // 0..383
    int k = idx - j*H;      // 0..127
    wihT[k*H3 + j] = wih[idx];
    whhT[k*H3 + j] = whh[idx];
  }
}

// core: acc[r][0..3] = X[r0+r][:] @ W[:, jq..jq+3], W row-major [128][128]
__device__ __forceinline__ void mvcore(const float* __restrict__ Xs, const float* __restrict__ W,
                                       int jq, int r0, float4 acc[4])
{
#pragma unroll
  for (int r = 0; r < 4; r++) acc[r] = make_float4(0.f,0.f,0.f,0.f);
#pragma unroll 2
  for (int k4 = 0; k4 < 32; k4++){
    const float* wp = W + 4*k4*H + jq;
    float4 w0 = *(const float4*)(wp);
    float4 w1 = *(const float4*)(wp + H);
    float4 w2 = *(const float4*)(wp + 2*H);
    float4 w3 = *(const float4*)(wp + 3*H);
#pragma unroll
    for (int r = 0; r < 4; r++){
      float4 x = *(const float4*)(Xs + (r0+r)*H + 4*k4);
      fma4(acc[r], x.x, w0); fma4(acc[r], x.y, w1);
      fma4(acc[r], x.z, w2); fma4(acc[r], x.w, w3);
    }
  }
}

// Y[r0..r0+3][jq..jq+3] = act( X@W + bias (+Y) ); each thread owns a 4x4 tile
__device__ __forceinline__ void mv4(const float* __restrict__ Xs, const float* __restrict__ W,
                                    const float* __restrict__ bias, float* __restrict__ Ys,
                                    int tid, bool act, bool addY)
{
  const int jq = (tid & 31) << 2;
  const int r0 = (tid >> 5) << 2;
  float4 acc[4];
  mvcore(Xs, W, jq, r0, acc);
  float4 bb = *(const float4*)(bias + jq);
#pragma unroll
  for (int r = 0; r < 4; r++){
    float* yp = Ys + (r0+r)*H + jq;
    float4 v = acc[r];
    v.x += bb.x; v.y += bb.y; v.z += bb.z; v.w += bb.w;
    if (addY){ float4 o = *(const float4*)yp; v.x+=o.x; v.y+=o.y; v.z+=o.z; v.w+=o.w; }
    if (act){ v.x=lrelu(v.x); v.y=lrelu(v.y); v.z=lrelu(v.z); v.w=lrelu(v.w); }
    *(float4*)yp = v;
  }
}

__global__ __launch_bounds__(256, 4) void graph_k(
    const float* __restrict__ emb_block, const float* __restrict__ emb_stem, const float* __restrict__ emb_bond,
    const float* __restrict__ conv_root, const float* __restrict__ conv_bias,
    const float* __restrict__ b2e_w1, const float* __restrict__ b2e_b1,
    const float* __restrict__ b2e_w2, const float* __restrict__ b2e_b2,
    const float* __restrict__ wihT, const float* __restrict__ whhT,
    const float* __restrict__ bih, const float* __restrict__ bhh,
    const float* __restrict__ s2p_w1, const float* __restrict__ s2p_b1,
    const float* __restrict__ s2p_w2, const float* __restrict__ s2p_b2,
    const float* __restrict__ s2p_w3, const float* __restrict__ s2p_b3,
    const float* __restrict__ g2p_w1, const float* __restrict__ g2p_b1,
    const float* __restrict__ g2p_w2, const float* __restrict__ g2p_b2,
    const int* __restrict__ x_ids, const int* __restrict__ stemtype_ids, const int* __restrict__ bond_ids,
    const int* __restrict__ edge_src, const int* __restrict__ edge_dst,
    const int* __restrict__ stems_local,
    float* __restrict__ stem_out, float* __restrict__ mol_out)
{
  __shared__ __align__(16) float h_s[ROWS*H];   // hidden state (16KB)
  __shared__ __align__(16) float m_s[ROWS*H];   // agg / conv out / head scratch (16KB)
  __shared__ float dot_s[GPB*EPG];
  __shared__ float deg_s[ROWS];
  __shared__ int src_s[GPB*EPG], dst_s[GPB*EPG], be0_s[GPB*EPG], be1_s[GPB*EPG];

  const int b = blockIdx.x;
  const int tid = threadIdx.x;
  const int jq = (tid & 31) << 2;   // col quad
  const int r0 = (tid >> 5) << 2;   // first of 4 owned rows

  // ---- per-graph structure ----
  if (tid < GPB*EPG){
    int slot = tid >> 4;
    int g = b*GPB + slot;
    int e = g*EPG + (tid & 15);
    src_s[tid] = edge_src[e] - g*NPG + slot*NPG;   // block row
    dst_s[tid] = edge_dst[e] - g*NPG + slot*NPG;
    be0_s[tid] = bond_ids[2*e];
    be1_s[tid] = bond_ids[2*e+1];
  }
  // x = emb_block[x_ids] into m_s
  for (int idx = tid; idx < ROWS*H; idx += 256){
    int row = idx >> 7;
    int g = b*GPB + (row >> 4);
    m_s[idx] = emb_block[x_ids[g*NPG + (row & 15)]*H + (idx & 127)];
  }
  __syncthreads();
  if (tid < ROWS){
    int slot = tid >> 4;
    float c = 0.f;
    for (int e = slot*EPG; e < slot*EPG + EPG; e++) c += (dst_s[e] == tid) ? 1.f : 0.f;
    deg_s[tid] = fmaxf(c, 1.f);
  }
  // ---- block2emb MLP ----
  mv4(m_s, b2e_w1, b2e_b1, h_s, tid, true, false);   // t = lrelu(x@w1+b1) -> h_s
  __syncthreads();
  {                                                   // h = t@w2+b2 (in-place on h_s, deferred write)
    float4 acc[4];
    mvcore(h_s, b2e_w2, jq, r0, acc);
    float4 bb = *(const float4*)(b2e_b2 + jq);
    __syncthreads();
#pragma unroll
    for (int r = 0; r < 4; r++){
      float4 v = acc[r];
      v.x += bb.x; v.y += bb.y; v.z += bb.z; v.w += bb.w;
      *(float4*)(h_s + (r0+r)*H + jq) = v;
    }
  }
  __syncthreads();

  // ---- 12 conv + GRU steps ----
  for (int step = 0; step < NSTEPS; step++){
    // zero agg (owner: thread (slot,col) owns column col of its graph)  ∥  per-edge dots
    {
      int slot = tid >> 7, col = tid & 127;
#pragma unroll
      for (int l = 0; l < NPG; l++) m_s[(slot*NPG + l)*H + col] = 0.f;
    }
    {
      int e = tid >> 3, sub = tid & 7;
      const float* b0 = emb_bond + be0_s[e]*H + sub*16;
      const float* xr = h_s + src_s[e]*H + sub*16;
      float p = 0.f;
#pragma unroll
      for (int q = 0; q < 4; q++){
        float4 xv = *(const float4*)(xr + 4*q);
        float4 bv = *(const float4*)(b0 + 4*q);
        p = fmaf(xv.x,bv.x, fmaf(xv.y,bv.y, fmaf(xv.z,bv.z, fmaf(xv.w,bv.w, p))));
      }
      p += __shfl_xor(p,1); p += __shfl_xor(p,2); p += __shfl_xor(p,4);
      if (sub == 0) dot_s[e] = p / deg_s[dst_s[e]];
    }
    __syncthreads();
    // scatter: agg[dst[e]][col] += dot[e]*be1[e][col]
    {
      int slot = tid >> 7, col = tid & 127;
#pragma unroll
      for (int le = 0; le < EPG; le++){
        int e = slot*EPG + le;
        m_s[dst_s[e]*H + col] += dot_s[e] * emb_bond[be1_s[e]*H + col];
      }
    }
    __syncthreads();
    // m = lrelu(h@conv_root + agg + bias)
    mv4(h_s, conv_root, conv_bias, m_s, tid, true, true);
    __syncthreads();
    // GRU: 3 phases, gates in registers; no LDS writes until the h update
    float4 rg[4], zg[4], ng[4];
#pragma unroll
    for (int p = 0; p < 3; p++){
      float4 ai[4], ah[4];
#pragma unroll
      for (int r = 0; r < 4; r++){ ai[r] = make_float4(0.f,0.f,0.f,0.f); ah[r] = make_float4(0.f,0.f,0.f,0.f); }
#pragma unroll 1
      for (int k4 = 0; k4 < 32; k4++){
        const float* wip = wihT + 4*k4*H3 + p*H + jq;
        const float* whp = whhT + 4*k4*H3 + p*H + jq;
        float4 wi0 = *(const float4*)(wip);
        float4 wi1 = *(const float4*)(wip + H3);
        float4 wi2 = *(const float4*)(wip + 2*H3);
        float4 wi3 = *(const float4*)(wip + 3*H3);
        float4 wh0 = *(const float4*)(whp);
        float4 wh1 = *(const float4*)(whp + H3);
        float4 wh2 = *(const float4*)(whp + 2*H3);
        float4 wh3 = *(const float4*)(whp + 3*H3);
#pragma unroll
        for (int r = 0; r < 4; r++){
          float4 xm = *(const float4*)(m_s + (r0+r)*H + 4*k4);
          float4 xh = *(const float4*)(h_s + (r0+r)*H + 4*k4);
          fma4(ai[r], xm.x, wi0); fma4(ai[r], xm.y, wi1);
          fma4(ai[r], xm.z, wi2); fma4(ai[r], xm.w, wi3);
          fma4(ah[r], xh.x, wh0); fma4(ah[r], xh.y, wh1);
          fma4(ah[r], xh.z, wh2); fma4(ah[r], xh.w, wh3);
        }
      }
      float4 bi = *(const float4*)(bih + p*H + jq);
      float4 bh = *(const float4*)(bhh + p*H + jq);
#pragma unroll
      for (int r = 0; r < 4; r++){
        float gix = ai[r].x + bi.x, giy = ai[r].y + bi.y, giz = ai[r].z + bi.z, giw = ai[r].w + bi.w;
        float ghx = ah[r].x + bh.x, ghy = ah[r].y + bh.y, ghz = ah[r].z + bh.z, ghw = ah[r].w + bh.w;
        if (p == 0){
          rg[r] = make_float4(sigm(gix+ghx), sigm(giy+ghy), sigm(giz+ghz), sigm(giw+ghw));
        } else if (p == 1){
          zg[r] = make_float4(sigm(gix+ghx), sigm(giy+ghy), sigm(giz+ghz), sigm(giw+ghw));
        } else {
          ng[r] = make_float4(tanhx(gix + rg[r].x*ghx), tanhx(giy + rg[r].y*ghy),
                              tanhx(giz + rg[r].z*ghz), tanhx(giw + rg[r].w*ghw));
        }
      }
    }
    __syncthreads();   // all gh reads of h_s complete
#pragma unroll
    for (int r = 0; r < 4; r++){
      float4* hp = (float4*)(h_s + (r0+r)*H + jq);
      float4 hv = *hp;
      hv.x = (1.f - zg[r].x)*ng[r].x + zg[r].x*hv.x;
      hv.y = (1.f - zg[r].y)*ng[r].y + zg[r].y*hv.y;
      hv.z = (1.f - zg[r].z)*ng[r].z + zg[r].z*hv.z;
      hv.w = (1.f - zg[r].w)*ng[r].w + zg[r].w*hv.w;
      *hp = hv;
    }
    __syncthreads();
  }

  // ---- stem head: 8 stems/block ----
  for (int idx = tid; idx < 8*256; idx += 256){
    int ls = idx >> 8, j = idx & 255;
    int sg = b*8 + ls;
    int slot = ls >> 2;
    m_s[idx] = (j < H) ? h_s[(slot*NPG + stems_local[sg])*H + j]
                       : emb_stem[stemtype_ids[sg]*H + (j - H)];
  }
  __syncthreads();
  {   // layer1: [8,256]@[256,128]; thread: 1 stem row x 4 cols
    int ls = tid >> 5;
    float4 acc = make_float4(0.f,0.f,0.f,0.f);
    const float* xr = m_s + ls*256;
    for (int k4 = 0; k4 < 64; k4++){
      float4 xv = *(const float4*)(xr + 4*k4);
      const float* wp = s2p_w1 + 4*k4*H + jq;
      float4 w0=*(const float4*)(wp), w1=*(const float4*)(wp+H), w2=*(const float4*)(wp+2*H), w3=*(const float4*)(wp+3*H);
      fma4(acc, xv.x, w0); fma4(acc, xv.y, w1); fma4(acc, xv.z, w2); fma4(acc, xv.w, w3);
    }
    float4 bb = *(const float4*)(s2p_b1 + jq);
    float* yp = m_s + 2048 + ls*H + jq;
    yp[0]=lrelu(acc.x+bb.x); yp[1]=lrelu(acc.y+bb.y); yp[2]=lrelu(acc.z+bb.z); yp[3]=lrelu(acc.w+bb.w);
  }
  __syncthreads();
  {   // layer2: [8,128]@[128,128]
    int ls = tid >> 5;
    float4 acc = make_float4(0.f,0.f,0.f,0.f);
    const float* xr = m_s + 2048 + ls*H;
    for (int k4 = 0; k4 < 32; k4++){
      float4 xv = *(const float4*)(xr + 4*k4);
      const float* wp = s2p_w2 + 4*k4*H + jq;
      float4 w0=*(const float4*)(wp), w1=*(const float4*)(wp+H), w2=*(const float4*)(wp+2*H), w3=*(const float4*)(wp+3*H);
      fma4(acc, xv.x, w0); fma4(acc, xv.y, w1); fma4(acc, xv.z, w2); fma4(acc, xv.w, w3);
    }
    float4 bb = *(const float4*)(s2p_b2 + jq);
    float* yp = m_s + 3072 + ls*H + jq;
    yp[0]=lrelu(acc.x+bb.x); yp[1]=lrelu(acc.y+bb.y); yp[2]=lrelu(acc.z+bb.z); yp[3]=lrelu(acc.w+bb.w);
  }
  __syncthreads();
  // layer3: [8,128]@[128,105]  ∥  mol pool (disjoint LDS regions)
  for (int o = tid; o < 8*OPS; o += 256){
    int s = o / OPS, j = o - s*OPS;
    float acc = s2p_b3[j];
    const float* xr = m_s + 3072 + s*H;
    for (int k = 0; k < H; k++) acc = fmaf(xr[k], s2p_w3[k*OPS + j], acc);
    stem_out[(b*8 + s)*OPS + j] = acc;
  }
  {   // mean pool -> m_s[0..255]
    int slot = tid >> 7, col = tid & 127;
    float a = 0.f;
    for (int i = 0; i < NPG; i++) a += h_s[(slot*NPG + i)*H + col];
    m_s[slot*H + col] = a * (1.0f/16.0f);
  }
  __syncthreads();
  {   // g2p layer1: [2,128]@[128,128]
    int slot = tid >> 7, col = tid & 127;
    float acc = g2p_b1[col];
    const float* xr = m_s + slot*H;
    for (int k = 0; k < H; k++) acc = fmaf(xr[k], g2p_w1[k*H + col], acc);
    m_s[256 + slot*H + col] = lrelu(acc);
  }
  __syncthreads();
  if (tid < GPB){
    float acc = g2p_b2[0];
    const float* xr = m_s + 256 + tid*H;
    for (int k = 0; k < H; k++) acc = fmaf(xr[k], g2p_w2[k], acc);
    mol_out[b*GPB + tid] = acc;
  }
}

extern "C" void kernel_launch(void* const* d_in, const int* in_sizes, int n_in,
                              void* d_out, int out_size, void* d_ws, size_t ws_size,
                              hipStream_t stream)
{
  (void)in_sizes; (void)n_in; (void)out_size; (void)ws_size;
  const float* emb_block = (const float*)d_in[0];
  const float* emb_stem  = (const float*)d_in[1];
  const float* emb_bond  = (const float*)d_in[2];
  const float* conv_root = (const float*)d_in[3];
  const float* conv_bias = (const float*)d_in[4];
  const float* b2e_w1 = (const float*)d_in[5];
  const float* b2e_b1 = (const float*)d_in[6];
  const float* b2e_w2 = (const float*)d_in[7];
  const float* b2e_b2 = (const float*)d_in[8];
  const float* gru_wih = (const float*)d_in[9];
  const float* gru_whh = (const float*)d_in[10];
  const float* gru_bih = (const float*)d_in[11];
  const float* gru_bhh = (const float*)d_in[12];
  const float* s2p_w1 = (const float*)d_in[13];
  const float* s2p_b1 = (const float*)d_in[14];
  const float* s2p_w2 = (const float*)d_in[15];
  const float* s2p_b2 = (const float*)d_in[16];
  const float* s2p_w3 = (const float*)d_in[17];
  const float* s2p_b3 = (const float*)d_in[18];
  const float* g2p_w1 = (const float*)d_in[19];
  const float* g2p_b1 = (const float*)d_in[20];
  const float* g2p_w2 = (const float*)d_in[21];
  const float* g2p_b2 = (const float*)d_in[22];
  const int* x_ids        = (const int*)d_in[23];
  const int* stemtype_ids = (const int*)d_in[24];
  const int* bond_ids     = (const int*)d_in[25];
  const int* edge_src     = (const int*)d_in[26];
  const int* edge_dst     = (const int*)d_in[27];
  const int* stems_local  = (const int*)d_in[30];

  float* wihT = (float*)d_ws;              // [128][384]
  float* whhT = wihT + 3*H*H;              // [128][384]
  float* stem_out = (float*)d_out;         // [4096][105]
  float* mol_out  = stem_out + 4096*OPS;

  transpose_k<<<192, 256, 0, stream>>>(gru_wih, gru_whh, wihT, whhT);
  graph_k<<<512, 256, 0, stream>>>(emb_block, emb_stem, emb_bond, conv_root, conv_bias,
      b2e_w1, b2e_b1, b2e_w2, b2e_b2, wihT, whhT, gru_bih, gru_bhh,
      s2p_w1, s2p_b1, s2p_w2, s2p_b2, s2p_w3, s2p_b3,
      g2p_w1, g2p_b1, g2p_w2, g2p_b2,
      x_ids, stemtype_ids, bond_ids, edge_src, edge_dst, stems_local,
      stem_out, mol_out);
}

// Round 48
// 818.530 us; speedup vs baseline: 1.3098x; 1.3098x over previous
//
#include <hip/hip_runtime.h>

#define H 128
#define H3 384
#define NPG 16
#define EPG 16
#define GPB 2
#define ROWS (GPB*NPG)      // 32 rows (nodes) per block
#define NSTEPS 12
#define OPS 105

__device__ __forceinline__ float lrelu(float x){ return x > 0.0f ? x : 0.01f*x; }
__device__ __forceinline__ float sigm(float x){ return 1.0f/(1.0f+__expf(-x)); }
__device__ __forceinline__ float tanhx(float x){
  x = fminf(15.f, fmaxf(-15.f, x));
  float e = __expf(2.f*x);
  return (e-1.f)/(e+1.f);
}

__device__ __forceinline__ void fma4(float4& a, float s, const float4& w){
  a.x = fmaf(s, w.x, a.x); a.y = fmaf(s, w.y, a.y);
  a.z = fmaf(s, w.z, a.z); a.w = fmaf(s, w.w, a.w);
}

// pre-transpose gru_wih/gru_whh [384,128] -> [128,384] (k-major) for coalesced matvec loads
__global__ void transpose_k(const float* __restrict__ wih, const float* __restrict__ whh,
                            float* __restrict__ wihT, float* __restrict__ whhT){
  int idx = blockIdx.x * 256 + threadIdx.x;
  if (idx < 3*H*H) {
    int j = idx / H;        // 0..383
    int k = idx - j*H;      // 0..127
    wihT[k*H3 + j] = wih[idx];
    whhT[k*H3 + j] = whh[idx];
  }
}

// core: acc[r][0..3] = X[r0+r][:] @ W[:, jq..jq+3], W row-major [128][128]
__device__ __forceinline__ void mvcore(const float* __restrict__ Xs, const float* __restrict__ W,
                                       int jq, int r0, float4 acc[4])
{
#pragma unroll
  for (int r = 0; r < 4; r++) acc[r] = make_float4(0.f,0.f,0.f,0.f);
#pragma unroll 2
  for (int k4 = 0; k4 < 32; k4++){
    const float* wp = W + 4*k4*H + jq;
    float4 w0 = *(const float4*)(wp);
    float4 w1 = *(const float4*)(wp + H);
    float4 w2 = *(const float4*)(wp + 2*H);
    float4 w3 = *(const float4*)(wp + 3*H);
#pragma unroll
    for (int r = 0; r < 4; r++){
      float4 x = *(const float4*)(Xs + (r0+r)*H + 4*k4);
      fma4(acc[r], x.x, w0); fma4(acc[r], x.y, w1);
      fma4(acc[r], x.z, w2); fma4(acc[r], x.w, w3);
    }
  }
}

// half-pass: acc[r] += X[r0+r][:] @ WT[:, col..col+3], WT k-major [128][384]
__device__ __forceinline__ void halfpass(const float* __restrict__ Xs, const float* __restrict__ WT,
                                         int col, int r0, float4 acc[4])
{
#pragma unroll 1
  for (int k4 = 0; k4 < 32; k4++){
    const float* wp = WT + 4*k4*H3 + col;
    float4 w0 = *(const float4*)(wp);
    float4 w1 = *(const float4*)(wp + H3);
    float4 w2 = *(const float4*)(wp + 2*H3);
    float4 w3 = *(const float4*)(wp + 3*H3);
#pragma unroll
    for (int r = 0; r < 4; r++){
      float4 x = *(const float4*)(Xs + (r0+r)*H + 4*k4);
      fma4(acc[r], x.x, w0); fma4(acc[r], x.y, w1);
      fma4(acc[r], x.z, w2); fma4(acc[r], x.w, w3);
    }
  }
}

// Y[r0..r0+3][jq..jq+3] = act( X@W + bias (+Y) ); each thread owns a 4x4 tile
__device__ __forceinline__ void mv4(const float* __restrict__ Xs, const float* __restrict__ W,
                                    const float* __restrict__ bias, float* __restrict__ Ys,
                                    int tid, bool act, bool addY)
{
  const int jq = (tid & 31) << 2;
  const int r0 = (tid >> 5) << 2;
  float4 acc[4];
  mvcore(Xs, W, jq, r0, acc);
  float4 bb = *(const float4*)(bias + jq);
#pragma unroll
  for (int r = 0; r < 4; r++){
    float* yp = Ys + (r0+r)*H + jq;
    float4 v = acc[r];
    v.x += bb.x; v.y += bb.y; v.z += bb.z; v.w += bb.w;
    if (addY){ float4 o = *(const float4*)yp; v.x+=o.x; v.y+=o.y; v.z+=o.z; v.w+=o.w; }
    if (act){ v.x=lrelu(v.x); v.y=lrelu(v.y); v.z=lrelu(v.z); v.w=lrelu(v.w); }
    *(float4*)yp = v;
  }
}

__global__ __launch_bounds__(256, 4) void graph_k(
    const float* __restrict__ emb_block, const float* __restrict__ emb_stem, const float* __restrict__ emb_bond,
    const float* __restrict__ conv_root, const float* __restrict__ conv_bias,
    const float* __restrict__ b2e_w1, const float* __restrict__ b2e_b1,
    const float* __restrict__ b2e_w2, const float* __restrict__ b2e_b2,
    const float* __restrict__ wihT, const float* __restrict__ whhT,
    const float* __restrict__ bih, const float* __restrict__ bhh,
    const float* __restrict__ s2p_w1, const float* __restrict__ s2p_b1,
    const float* __restrict__ s2p_w2, const float* __restrict__ s2p_b2,
    const float* __restrict__ s2p_w3, const float* __restrict__ s2p_b3,
    const float* __restrict__ g2p_w1, const float* __restrict__ g2p_b1,
    const float* __restrict__ g2p_w2, const float* __restrict__ g2p_b2,
    const int* __restrict__ x_ids, const int* __restrict__ stemtype_ids, const int* __restrict__ bond_ids,
    const int* __restrict__ edge_src, const int* __restrict__ edge_dst,
    const int* __restrict__ stems_local,
    float* __restrict__ stem_out, float* __restrict__ mol_out)
{
  __shared__ __align__(16) float h_s[ROWS*H];   // hidden state (16KB)
  __shared__ __align__(16) float m_s[ROWS*H];   // agg / conv out / head scratch (16KB)
  __shared__ float dot_s[GPB*EPG];
  __shared__ float deg_s[ROWS];
  __shared__ int src_s[GPB*EPG], dst_s[GPB*EPG], be0_s[GPB*EPG], be1_s[GPB*EPG];

  const int b = blockIdx.x;
  const int tid = threadIdx.x;
  const int jq = (tid & 31) << 2;   // col quad
  const int r0 = (tid >> 5) << 2;   // first of 4 owned rows

  // ---- per-graph structure ----
  if (tid < GPB*EPG){
    int slot = tid >> 4;
    int g = b*GPB + slot;
    int e = g*EPG + (tid & 15);
    src_s[tid] = edge_src[e] - g*NPG + slot*NPG;   // block row
    dst_s[tid] = edge_dst[e] - g*NPG + slot*NPG;
    be0_s[tid] = bond_ids[2*e];
    be1_s[tid] = bond_ids[2*e+1];
  }
  // x = emb_block[x_ids] into m_s
  for (int idx = tid; idx < ROWS*H; idx += 256){
    int row = idx >> 7;
    int g = b*GPB + (row >> 4);
    m_s[idx] = emb_block[x_ids[g*NPG + (row & 15)]*H + (idx & 127)];
  }
  __syncthreads();
  if (tid < ROWS){
    int slot = tid >> 4;
    float c = 0.f;
    for (int e = slot*EPG; e < slot*EPG + EPG; e++) c += (dst_s[e] == tid) ? 1.f : 0.f;
    deg_s[tid] = fmaxf(c, 1.f);
  }
  // ---- block2emb MLP ----
  mv4(m_s, b2e_w1, b2e_b1, h_s, tid, true, false);   // t = lrelu(x@w1+b1) -> h_s
  __syncthreads();
  {                                                   // h = t@w2+b2 (in-place on h_s, deferred write)
    float4 acc[4];
    mvcore(h_s, b2e_w2, jq, r0, acc);
    float4 bb = *(const float4*)(b2e_b2 + jq);
    __syncthreads();
#pragma unroll
    for (int r = 0; r < 4; r++){
      float4 v = acc[r];
      v.x += bb.x; v.y += bb.y; v.z += bb.z; v.w += bb.w;
      *(float4*)(h_s + (r0+r)*H + jq) = v;
    }
  }
  __syncthreads();

  // ---- 12 conv + GRU steps ----
  for (int step = 0; step < NSTEPS; step++){
    // zero agg (owner: thread (slot,col) owns column col of its graph)  ∥  per-edge dots
    {
      int slot = tid >> 7, col = tid & 127;
#pragma unroll
      for (int l = 0; l < NPG; l++) m_s[(slot*NPG + l)*H + col] = 0.f;
    }
    {
      int e = tid >> 3, sub = tid & 7;
      const float* b0 = emb_bond + be0_s[e]*H + sub*16;
      const float* xr = h_s + src_s[e]*H + sub*16;
      float p = 0.f;
#pragma unroll
      for (int q = 0; q < 4; q++){
        float4 xv = *(const float4*)(xr + 4*q);
        float4 bv = *(const float4*)(b0 + 4*q);
        p = fmaf(xv.x,bv.x, fmaf(xv.y,bv.y, fmaf(xv.z,bv.z, fmaf(xv.w,bv.w, p))));
      }
      p += __shfl_xor(p,1); p += __shfl_xor(p,2); p += __shfl_xor(p,4);
      if (sub == 0) dot_s[e] = p / deg_s[dst_s[e]];
    }
    __syncthreads();
    // scatter: agg[dst[e]][col] += dot[e]*be1[e][col]
    {
      int slot = tid >> 7, col = tid & 127;
#pragma unroll
      for (int le = 0; le < EPG; le++){
        int e = slot*EPG + le;
        m_s[dst_s[e]*H + col] += dot_s[e] * emb_bond[be1_s[e]*H + col];
      }
    }
    __syncthreads();
    // m = lrelu(h@conv_root + agg + bias)
    mv4(h_s, conv_root, conv_bias, m_s, tid, true, true);
    __syncthreads();
    // GRU: register-lean — each gate is two half-passes sharing ONE accumulator
    float4 rg[4], zg[4], ng[4];
    {   // r gate: acc = m@Wih_r + h@Whh_r
      float4 acc[4];
#pragma unroll
      for (int r = 0; r < 4; r++) acc[r] = make_float4(0.f,0.f,0.f,0.f);
      halfpass(m_s, wihT, jq, r0, acc);
      halfpass(h_s, whhT, jq, r0, acc);
      float4 bi = *(const float4*)(bih + jq);
      float4 bh = *(const float4*)(bhh + jq);
#pragma unroll
      for (int r = 0; r < 4; r++){
        rg[r] = make_float4(sigm(acc[r].x + bi.x + bh.x), sigm(acc[r].y + bi.y + bh.y),
                            sigm(acc[r].z + bi.z + bh.z), sigm(acc[r].w + bi.w + bh.w));
      }
    }
    {   // z gate
      float4 acc[4];
#pragma unroll
      for (int r = 0; r < 4; r++) acc[r] = make_float4(0.f,0.f,0.f,0.f);
      halfpass(m_s, wihT, H + jq, r0, acc);
      halfpass(h_s, whhT, H + jq, r0, acc);
      float4 bi = *(const float4*)(bih + H + jq);
      float4 bh = *(const float4*)(bhh + H + jq);
#pragma unroll
      for (int r = 0; r < 4; r++){
        zg[r] = make_float4(sigm(acc[r].x + bi.x + bh.x), sigm(acc[r].y + bi.y + bh.y),
                            sigm(acc[r].z + bi.z + bh.z), sigm(acc[r].w + bi.w + bh.w));
      }
    }
    {   // n gate: gh = h@Whh_n + bhh; fold r*gh into rg (dead); then acc = m@Wih_n
      float4 acc[4];
#pragma unroll
      for (int r = 0; r < 4; r++) acc[r] = make_float4(0.f,0.f,0.f,0.f);
      halfpass(h_s, whhT, 2*H + jq, r0, acc);
      float4 bh = *(const float4*)(bhh + 2*H + jq);
#pragma unroll
      for (int r = 0; r < 4; r++){
        rg[r] = make_float4(rg[r].x*(acc[r].x + bh.x), rg[r].y*(acc[r].y + bh.y),
                            rg[r].z*(acc[r].z + bh.z), rg[r].w*(acc[r].w + bh.w));
        acc[r] = make_float4(0.f,0.f,0.f,0.f);
      }
      halfpass(m_s, wihT, 2*H + jq, r0, acc);
      float4 bi = *(const float4*)(bih + 2*H + jq);
#pragma unroll
      for (int r = 0; r < 4; r++){
        ng[r] = make_float4(tanhx(acc[r].x + bi.x + rg[r].x), tanhx(acc[r].y + bi.y + rg[r].y),
                            tanhx(acc[r].z + bi.z + rg[r].z), tanhx(acc[r].w + bi.w + rg[r].w));
      }
    }
    __syncthreads();   // all reads of h_s complete
#pragma unroll
    for (int r = 0; r < 4; r++){
      float4* hp = (float4*)(h_s + (r0+r)*H + jq);
      float4 hv = *hp;
      hv.x = (1.f - zg[r].x)*ng[r].x + zg[r].x*hv.x;
      hv.y = (1.f - zg[r].y)*ng[r].y + zg[r].y*hv.y;
      hv.z = (1.f - zg[r].z)*ng[r].z + zg[r].z*hv.z;
      hv.w = (1.f - zg[r].w)*ng[r].w + zg[r].w*hv.w;
      *hp = hv;
    }
    __syncthreads();
  }

  // ---- stem head: 8 stems/block ----
  for (int idx = tid; idx < 8*256; idx += 256){
    int ls = idx >> 8, j = idx & 255;
    int sg = b*8 + ls;
    int slot = ls >> 2;
    m_s[idx] = (j < H) ? h_s[(slot*NPG + stems_local[sg])*H + j]
                       : emb_stem[stemtype_ids[sg]*H + (j - H)];
  }
  __syncthreads();
  {   // layer1: [8,256]@[256,128]; thread: 1 stem row x 4 cols
    int ls = tid >> 5;
    float4 acc = make_float4(0.f,0.f,0.f,0.f);
    const float* xr = m_s + ls*256;
    for (int k4 = 0; k4 < 64; k4++){
      float4 xv = *(const float4*)(xr + 4*k4);
      const float* wp = s2p_w1 + 4*k4*H + jq;
      float4 w0=*(const float4*)(wp), w1=*(const float4*)(wp+H), w2=*(const float4*)(wp+2*H), w3=*(const float4*)(wp+3*H);
      fma4(acc, xv.x, w0); fma4(acc, xv.y, w1); fma4(acc, xv.z, w2); fma4(acc, xv.w, w3);
    }
    float4 bb = *(const float4*)(s2p_b1 + jq);
    float* yp = m_s + 2048 + ls*H + jq;
    yp[0]=lrelu(acc.x+bb.x); yp[1]=lrelu(acc.y+bb.y); yp[2]=lrelu(acc.z+bb.z); yp[3]=lrelu(acc.w+bb.w);
  }
  __syncthreads();
  {   // layer2: [8,128]@[128,128]
    int ls = tid >> 5;
    float4 acc = make_float4(0.f,0.f,0.f,0.f);
    const float* xr = m_s + 2048 + ls*H;
    for (int k4 = 0; k4 < 32; k4++){
      float4 xv = *(const float4*)(xr + 4*k4);
      const float* wp = s2p_w2 + 4*k4*H + jq;
      float4 w0=*(const float4*)(wp), w1=*(const float4*)(wp+H), w2=*(const float4*)(wp+2*H), w3=*(const float4*)(wp+3*H);
      fma4(acc, xv.x, w0); fma4(acc, xv.y, w1); fma4(acc, xv.z, w2); fma4(acc, xv.w, w3);
    }
    float4 bb = *(const float4*)(s2p_b2 + jq);
    float* yp = m_s + 3072 + ls*H + jq;
    yp[0]=lrelu(acc.x+bb.x); yp[1]=lrelu(acc.y+bb.y); yp[2]=lrelu(acc.z+bb.z); yp[3]=lrelu(acc.w+bb.w);
  }
  __syncthreads();
  // layer3: [8,128]@[128,105]  ∥  mol pool (disjoint LDS regions)
  for (int o = tid; o < 8*OPS; o += 256){
    int s = o / OPS, j = o - s*OPS;
    float acc = s2p_b3[j];
    const float* xr = m_s + 3072 + s*H;
    for (int k = 0; k < H; k++) acc = fmaf(xr[k], s2p_w3[k*OPS + j], acc);
    stem_out[(b*8 + s)*OPS + j] = acc;
  }
  {   // mean pool -> m_s[0..255]
    int slot = tid >> 7, col = tid & 127;
    float a = 0.f;
    for (int i = 0; i < NPG; i++) a += h_s[(slot*NPG + i)*H + col];
    m_s[slot*H + col] = a * (1.0f/16.0f);
  }
  __syncthreads();
  {   // g2p layer1: [2,128]@[128,128]
    int slot = tid >> 7, col = tid & 127;
    float acc = g2p_b1[col];
    const float* xr = m_s + slot*H;
    for (int k = 0; k < H; k++) acc = fmaf(xr[k], g2p_w1[k*H + col], acc);
    m_s[256 + slot*H + col] = lrelu(acc);
  }
  __syncthreads();
  if (tid < GPB){
    float acc = g2p_b2[0];
    const float* xr = m_s + 256 + tid*H;
    for (int k = 0; k < H; k++) acc = fmaf(xr[k], g2p_w2[k], acc);
    mol_out[b*GPB + tid] = acc;
  }
}

extern "C" void kernel_launch(void* const* d_in, const int* in_sizes, int n_in,
                              void* d_out, int out_size, void* d_ws, size_t ws_size,
                              hipStream_t stream)
{
  (void)in_sizes; (void)n_in; (void)out_size; (void)ws_size;
  const float* emb_block = (const float*)d_in[0];
  const float* emb_stem  = (const float*)d_in[1];
  const float* emb_bond  = (const float*)d_in[2];
  const float* conv_root = (const float*)d_in[3];
  const float* conv_bias = (const float*)d_in[4];
  const float* b2e_w1 = (const float*)d_in[5];
  const float* b2e_b1 = (const float*)d_in[6];
  const float* b2e_w2 = (const float*)d_in[7];
  const float* b2e_b2 = (const float*)d_in[8];
  const float* gru_wih = (const float*)d_in[9];
  const float* gru_whh = (const float*)d_in[10];
  const float* gru_bih = (const float*)d_in[11];
  const float* gru_bhh = (const float*)d_in[12];
  const float* s2p_w1 = (const float*)d_in[13];
  const float* s2p_b1 = (const float*)d_in[14];
  const float* s2p_w2 = (const float*)d_in[15];
  const float* s2p_b2 = (const float*)d_in[16];
  const float* s2p_w3 = (const float*)d_in[17];
  const float* s2p_b3 = (const float*)d_in[18];
  const float* g2p_w1 = (const float*)d_in[19];
  const float* g2p_b1 = (const float*)d_in[20];
  const float* g2p_w2 = (const float*)d_in[21];
  const float* g2p_b2 = (const float*)d_in[22];
  const int* x_ids        = (const int*)d_in[23];
  const int* stemtype_ids = (const int*)d_in[24];
  const int* bond_ids     = (const int*)d_in[25];
  const int* edge_src     = (const int*)d_in[26];
  const int* edge_dst     = (const int*)d_in[27];
  const int* stems_local  = (const int*)d_in[30];

  float* wihT = (float*)d_ws;              // [128][384]
  float* whhT = wihT + 3*H*H;              // [128][384]
  float* stem_out = (float*)d_out;         // [4096][105]
  float* mol_out  = stem_out + 4096*OPS;

  transpose_k<<<192, 256, 0, stream>>>(gru_wih, gru_whh, wihT, whhT);
  graph_k<<<512, 256, 0, stream>>>(emb_block, emb_stem, emb_bond, conv_root, conv_bias,
      b2e_w1, b2e_b1, b2e_w2, b2e_b2, wihT, whhT, gru_bih, gru_bhh,
      s2p_w1, s2p_b1, s2p_w2, s2p_b2, s2p_w3, s2p_b3,
      g2p_w1, g2p_b1, g2p_w2, g2p_b2,
      x_ids, stemtype_ids, bond_ids, edge_src, edge_dst, stems_local,
      stem_out, mol_out);
}

// Round 49
// 780.670 us; speedup vs baseline: 1.3734x; 1.0485x over previous
//
#include <hip/hip_runtime.h>

#define H 128
#define H3 384
#define NPG 16
#define EPG 16
#define GPB 2
#define ROWS (GPB*NPG)      // 32 rows (nodes) per block
#define NSTEPS 12
#define OPS 105

__device__ __forceinline__ float lrelu(float x){ return x > 0.0f ? x : 0.01f*x; }
__device__ __forceinline__ float sigm(float x){ return 1.0f/(1.0f+__expf(-x)); }
__device__ __forceinline__ float tanhx(float x){
  x = fminf(15.f, fmaxf(-15.f, x));
  float e = __expf(2.f*x);
  return (e-1.f)/(e+1.f);
}

__device__ __forceinline__ void fma4(float4& a, float s, const float4& w){
  a.x = fmaf(s, w.x, a.x); a.y = fmaf(s, w.y, a.y);
  a.z = fmaf(s, w.z, a.z); a.w = fmaf(s, w.w, a.w);
}

// pre-transpose gru_wih/gru_whh [384,128] -> [128,384] (k-major) for coalesced matvec loads
__global__ void transpose_k(const float* __restrict__ wih, const float* __restrict__ whh,
                            float* __restrict__ wihT, float* __restrict__ whhT){
  int idx = blockIdx.x * 256 + threadIdx.x;
  if (idx < 3*H*H) {
    int j = idx / H;        // 0..383
    int k = idx - j*H;      // 0..127
    wihT[k*H3 + j] = wih[idx];
    whhT[k*H3 + j] = whh[idx];
  }
}

// core: acc[r][0..3] = X[r0+r][:] @ W[:, jq..jq+3], W row-major [128][128]
__device__ __forceinline__ void mvcore(const float* __restrict__ Xs, const float* __restrict__ W,
                                       int jq, int r0, float4 acc[4])
{
#pragma unroll
  for (int r = 0; r < 4; r++) acc[r] = make_float4(0.f,0.f,0.f,0.f);
#pragma unroll 4
  for (int k4 = 0; k4 < 32; k4++){
    const float* wp = W + 4*k4*H + jq;
    float4 w0 = *(const float4*)(wp);
    float4 w1 = *(const float4*)(wp + H);
    float4 w2 = *(const float4*)(wp + 2*H);
    float4 w3 = *(const float4*)(wp + 3*H);
#pragma unroll
    for (int r = 0; r < 4; r++){
      float4 x = *(const float4*)(Xs + (r0+r)*H + 4*k4);
      fma4(acc[r], x.x, w0); fma4(acc[r], x.y, w1);
      fma4(acc[r], x.z, w2); fma4(acc[r], x.w, w3);
    }
  }
}

// half-pass: acc[r] += X[r0+r][:] @ WT[:, col..col+3], WT k-major [128][384]
__device__ __forceinline__ void halfpass(const float* __restrict__ Xs, const float* __restrict__ WT,
                                         int col, int r0, float4 acc[4])
{
#pragma unroll 4
  for (int k4 = 0; k4 < 32; k4++){
    const float* wp = WT + 4*k4*H3 + col;
    float4 w0 = *(const float4*)(wp);
    float4 w1 = *(const float4*)(wp + H3);
    float4 w2 = *(const float4*)(wp + 2*H3);
    float4 w3 = *(const float4*)(wp + 3*H3);
#pragma unroll
    for (int r = 0; r < 4; r++){
      float4 x = *(const float4*)(Xs + (r0+r)*H + 4*k4);
      fma4(acc[r], x.x, w0); fma4(acc[r], x.y, w1);
      fma4(acc[r], x.z, w2); fma4(acc[r], x.w, w3);
    }
  }
}

// Y[r0..r0+3][jq..jq+3] = act( X@W + bias (+Y) ); each thread owns a 4x4 tile
__device__ __forceinline__ void mv4(const float* __restrict__ Xs, const float* __restrict__ W,
                                    const float* __restrict__ bias, float* __restrict__ Ys,
                                    int tid, bool act, bool addY)
{
  const int jq = (tid & 31) << 2;
  const int r0 = (tid >> 5) << 2;
  float4 acc[4];
  mvcore(Xs, W, jq, r0, acc);
  float4 bb = *(const float4*)(bias + jq);
#pragma unroll
  for (int r = 0; r < 4; r++){
    float* yp = Ys + (r0+r)*H + jq;
    float4 v = acc[r];
    v.x += bb.x; v.y += bb.y; v.z += bb.z; v.w += bb.w;
    if (addY){ float4 o = *(const float4*)yp; v.x+=o.x; v.y+=o.y; v.z+=o.z; v.w+=o.w; }
    if (act){ v.x=lrelu(v.x); v.y=lrelu(v.y); v.z=lrelu(v.z); v.w=lrelu(v.w); }
    *(float4*)yp = v;
  }
}

__global__ __launch_bounds__(256, 2) void graph_k(
    const float* __restrict__ emb_block, const float* __restrict__ emb_stem, const float* __restrict__ emb_bond,
    const float* __restrict__ conv_root, const float* __restrict__ conv_bias,
    const float* __restrict__ b2e_w1, const float* __restrict__ b2e_b1,
    const float* __restrict__ b2e_w2, const float* __restrict__ b2e_b2,
    const float* __restrict__ wihT, const float* __restrict__ whhT,
    const float* __restrict__ bih, const float* __restrict__ bhh,
    const float* __restrict__ s2p_w1, const float* __restrict__ s2p_b1,
    const float* __restrict__ s2p_w2, const float* __restrict__ s2p_b2,
    const float* __restrict__ s2p_w3, const float* __restrict__ s2p_b3,
    const float* __restrict__ g2p_w1, const float* __restrict__ g2p_b1,
    const float* __restrict__ g2p_w2, const float* __restrict__ g2p_b2,
    const int* __restrict__ x_ids, const int* __restrict__ stemtype_ids, const int* __restrict__ bond_ids,
    const int* __restrict__ edge_src, const int* __restrict__ edge_dst,
    const int* __restrict__ stems_local,
    float* __restrict__ stem_out, float* __restrict__ mol_out)
{
  __shared__ __align__(16) float h_s[ROWS*H];   // hidden state (16KB)
  __shared__ __align__(16) float m_s[ROWS*H];   // agg / conv out / head scratch (16KB)
  __shared__ float dot_s[GPB*EPG];
  __shared__ float deg_s[ROWS];
  __shared__ int src_s[GPB*EPG], dst_s[GPB*EPG], be0_s[GPB*EPG], be1_s[GPB*EPG];

  const int b = blockIdx.x;
  const int tid = threadIdx.x;
  const int jq = (tid & 31) << 2;   // col quad
  const int r0 = (tid >> 5) << 2;   // first of 4 owned rows

  // ---- per-graph structure ----
  if (tid < GPB*EPG){
    int slot = tid >> 4;
    int g = b*GPB + slot;
    int e = g*EPG + (tid & 15);
    src_s[tid] = edge_src[e] - g*NPG + slot*NPG;   // block row
    dst_s[tid] = edge_dst[e] - g*NPG + slot*NPG;
    be0_s[tid] = bond_ids[2*e];
    be1_s[tid] = bond_ids[2*e+1];
  }
  // x = emb_block[x_ids] into m_s
  for (int idx = tid; idx < ROWS*H; idx += 256){
    int row = idx >> 7;
    int g = b*GPB + (row >> 4);
    m_s[idx] = emb_block[x_ids[g*NPG + (row & 15)]*H + (idx & 127)];
  }
  __syncthreads();
  if (tid < ROWS){
    int slot = tid >> 4;
    float c = 0.f;
    for (int e = slot*EPG; e < slot*EPG + EPG; e++) c += (dst_s[e] == tid) ? 1.f : 0.f;
    deg_s[tid] = fmaxf(c, 1.f);
  }
  // ---- block2emb MLP ----
  mv4(m_s, b2e_w1, b2e_b1, h_s, tid, true, false);   // t = lrelu(x@w1+b1) -> h_s
  __syncthreads();
  {                                                   // h = t@w2+b2 (in-place on h_s, deferred write)
    float4 acc[4];
    mvcore(h_s, b2e_w2, jq, r0, acc);
    float4 bb = *(const float4*)(b2e_b2 + jq);
    __syncthreads();
#pragma unroll
    for (int r = 0; r < 4; r++){
      float4 v = acc[r];
      v.x += bb.x; v.y += bb.y; v.z += bb.z; v.w += bb.w;
      *(float4*)(h_s + (r0+r)*H + jq) = v;
    }
  }
  __syncthreads();

  // ---- 12 conv + GRU steps ----
  for (int step = 0; step < NSTEPS; step++){
    // zero agg (owner: thread (slot,col) owns column col of its graph)  ∥  per-edge dots
    {
      int slot = tid >> 7, col = tid & 127;
#pragma unroll
      for (int l = 0; l < NPG; l++) m_s[(slot*NPG + l)*H + col] = 0.f;
    }
    {
      int e = tid >> 3, sub = tid & 7;
      const float* b0 = emb_bond + be0_s[e]*H + sub*16;
      const float* xr = h_s + src_s[e]*H + sub*16;
      float p = 0.f;
#pragma unroll
      for (int q = 0; q < 4; q++){
        float4 xv = *(const float4*)(xr + 4*q);
        float4 bv = *(const float4*)(b0 + 4*q);
        p = fmaf(xv.x,bv.x, fmaf(xv.y,bv.y, fmaf(xv.z,bv.z, fmaf(xv.w,bv.w, p))));
      }
      p += __shfl_xor(p,1); p += __shfl_xor(p,2); p += __shfl_xor(p,4);
      if (sub == 0) dot_s[e] = p / deg_s[dst_s[e]];
    }
    __syncthreads();
    // scatter: agg[dst[e]][col] += dot[e]*be1[e][col]
    {
      int slot = tid >> 7, col = tid & 127;
#pragma unroll
      for (int le = 0; le < EPG; le++){
        int e = slot*EPG + le;
        m_s[dst_s[e]*H + col] += dot_s[e] * emb_bond[be1_s[e]*H + col];
      }
    }
    __syncthreads();
    // m = lrelu(h@conv_root + agg + bias)
    mv4(h_s, conv_root, conv_bias, m_s, tid, true, true);
    __syncthreads();
    // GRU: register-lean — each gate is two half-passes sharing ONE accumulator
    float4 rg[4], zg[4], ng[4];
    {   // r gate: acc = m@Wih_r + h@Whh_r
      float4 acc[4];
#pragma unroll
      for (int r = 0; r < 4; r++) acc[r] = make_float4(0.f,0.f,0.f,0.f);
      halfpass(m_s, wihT, jq, r0, acc);
      halfpass(h_s, whhT, jq, r0, acc);
      float4 bi = *(const float4*)(bih + jq);
      float4 bh = *(const float4*)(bhh + jq);
#pragma unroll
      for (int r = 0; r < 4; r++){
        rg[r] = make_float4(sigm(acc[r].x + bi.x + bh.x), sigm(acc[r].y + bi.y + bh.y),
                            sigm(acc[r].z + bi.z + bh.z), sigm(acc[r].w + bi.w + bh.w));
      }
    }
    {   // z gate
      float4 acc[4];
#pragma unroll
      for (int r = 0; r < 4; r++) acc[r] = make_float4(0.f,0.f,0.f,0.f);
      halfpass(m_s, wihT, H + jq, r0, acc);
      halfpass(h_s, whhT, H + jq, r0, acc);
      float4 bi = *(const float4*)(bih + H + jq);
      float4 bh = *(const float4*)(bhh + H + jq);
#pragma unroll
      for (int r = 0; r < 4; r++){
        zg[r] = make_float4(sigm(acc[r].x + bi.x + bh.x), sigm(acc[r].y + bi.y + bh.y),
                            sigm(acc[r].z + bi.z + bh.z), sigm(acc[r].w + bi.w + bh.w));
      }
    }
    {   // n gate: gh = h@Whh_n + bhh; fold r*gh into rg (dead); then acc = m@Wih_n
      float4 acc[4];
#pragma unroll
      for (int r = 0; r < 4; r++) acc[r] = make_float4(0.f,0.f,0.f,0.f);
      halfpass(h_s, whhT, 2*H + jq, r0, acc);
      float4 bh = *(const float4*)(bhh + 2*H + jq);
#pragma unroll
      for (int r = 0; r < 4; r++){
        rg[r] = make_float4(rg[r].x*(acc[r].x + bh.x), rg[r].y*(acc[r].y + bh.y),
                            rg[r].z*(acc[r].z + bh.z), rg[r].w*(acc[r].w + bh.w));
        acc[r] = make_float4(0.f,0.f,0.f,0.f);
      }
      halfpass(m_s, wihT, 2*H + jq, r0, acc);
      float4 bi = *(const float4*)(bih + 2*H + jq);
#pragma unroll
      for (int r = 0; r < 4; r++){
        ng[r] = make_float4(tanhx(acc[r].x + bi.x + rg[r].x), tanhx(acc[r].y + bi.y + rg[r].y),
                            tanhx(acc[r].z + bi.z + rg[r].z), tanhx(acc[r].w + bi.w + rg[r].w));
      }
    }
    __syncthreads();   // all reads of h_s complete
#pragma unroll
    for (int r = 0; r < 4; r++){
      float4* hp = (float4*)(h_s + (r0+r)*H + jq);
      float4 hv = *hp;
      hv.x = (1.f - zg[r].x)*ng[r].x + zg[r].x*hv.x;
      hv.y = (1.f - zg[r].y)*ng[r].y + zg[r].y*hv.y;
      hv.z = (1.f - zg[r].z)*ng[r].z + zg[r].z*hv.z;
      hv.w = (1.f - zg[r].w)*ng[r].w + zg[r].w*hv.w;
      *hp = hv;
    }
    __syncthreads();
  }

  // ---- stem head: 8 stems/block ----
  for (int idx = tid; idx < 8*256; idx += 256){
    int ls = idx >> 8, j = idx & 255;
    int sg = b*8 + ls;
    int slot = ls >> 2;
    m_s[idx] = (j < H) ? h_s[(slot*NPG + stems_local[sg])*H + j]
                       : emb_stem[stemtype_ids[sg]*H + (j - H)];
  }
  __syncthreads();
  {   // layer1: [8,256]@[256,128]; thread: 1 stem row x 4 cols
    int ls = tid >> 5;
    float4 acc = make_float4(0.f,0.f,0.f,0.f);
    const float* xr = m_s + ls*256;
    for (int k4 = 0; k4 < 64; k4++){
      float4 xv = *(const float4*)(xr + 4*k4);
      const float* wp = s2p_w1 + 4*k4*H + jq;
      float4 w0=*(const float4*)(wp), w1=*(const float4*)(wp+H), w2=*(const float4*)(wp+2*H), w3=*(const float4*)(wp+3*H);
      fma4(acc, xv.x, w0); fma4(acc, xv.y, w1); fma4(acc, xv.z, w2); fma4(acc, xv.w, w3);
    }
    float4 bb = *(const float4*)(s2p_b1 + jq);
    float* yp = m_s + 2048 + ls*H + jq;
    yp[0]=lrelu(acc.x+bb.x); yp[1]=lrelu(acc.y+bb.y); yp[2]=lrelu(acc.z+bb.z); yp[3]=lrelu(acc.w+bb.w);
  }
  __syncthreads();
  {   // layer2: [8,128]@[128,128]
    int ls = tid >> 5;
    float4 acc = make_float4(0.f,0.f,0.f,0.f);
    const float* xr = m_s + 2048 + ls*H;
    for (int k4 = 0; k4 < 32; k4++){
      float4 xv = *(const float4*)(xr + 4*k4);
      const float* wp = s2p_w2 + 4*k4*H + jq;
      float4 w0=*(const float4*)(wp), w1=*(const float4*)(wp+H), w2=*(const float4*)(wp+2*H), w3=*(const float4*)(wp+3*H);
      fma4(acc, xv.x, w0); fma4(acc, xv.y, w1); fma4(acc, xv.z, w2); fma4(acc, xv.w, w3);
    }
    float4 bb = *(const float4*)(s2p_b2 + jq);
    float* yp = m_s + 3072 + ls*H + jq;
    yp[0]=lrelu(acc.x+bb.x); yp[1]=lrelu(acc.y+bb.y); yp[2]=lrelu(acc.z+bb.z); yp[3]=lrelu(acc.w+bb.w);
  }
  __syncthreads();
  // layer3: [8,128]@[128,105]  ∥  mol pool (disjoint LDS regions)
  for (int o = tid; o < 8*OPS; o += 256){
    int s = o / OPS, j = o - s*OPS;
    float acc = s2p_b3[j];
    const float* xr = m_s + 3072 + s*H;
    for (int k = 0; k < H; k++) acc = fmaf(xr[k], s2p_w3[k*OPS + j], acc);
    stem_out[(b*8 + s)*OPS + j] = acc;
  }
  {   // mean pool -> m_s[0..255]
    int slot = tid >> 7, col = tid & 127;
    float a = 0.f;
    for (int i = 0; i < NPG; i++) a += h_s[(slot*NPG + i)*H + col];
    m_s[slot*H + col] = a * (1.0f/16.0f);
  }
  __syncthreads();
  {   // g2p layer1: [2,128]@[128,128]
    int slot = tid >> 7, col = tid & 127;
    float acc = g2p_b1[col];
    const float* xr = m_s + slot*H;
    for (int k = 0; k < H; k++) acc = fmaf(xr[k], g2p_w1[k*H + col], acc);
    m_s[256 + slot*H + col] = lrelu(acc);
  }
  __syncthreads();
  if (tid < GPB){
    float acc = g2p_b2[0];
    const float* xr = m_s + 256 + tid*H;
    for (int k = 0; k < H; k++) acc = fmaf(xr[k], g2p_w2[k], acc);
    mol_out[b*GPB + tid] = acc;
  }
}

extern "C" void kernel_launch(void* const* d_in, const int* in_sizes, int n_in,
                              void* d_out, int out_size, void* d_ws, size_t ws_size,
                              hipStream_t stream)
{
  (void)in_sizes; (void)n_in; (void)out_size; (void)ws_size;
  const float* emb_block = (const float*)d_in[0];
  const float* emb_stem  = (const float*)d_in[1];
  const float* emb_bond  = (const float*)d_in[2];
  const float* conv_root = (const float*)d_in[3];
  const float* conv_bias = (const float*)d_in[4];
  const float* b2e_w1 = (const float*)d_in[5];
  const float* b2e_b1 = (const float*)d_in[6];
  const float* b2e_w2 = (const float*)d_in[7];
  const float* b2e_b2 = (const float*)d_in[8];
  const float* gru_wih = (const float*)d_in[9];
  const float* gru_whh = (const float*)d_in[10];
  const float* gru_bih = (const float*)d_in[11];
  const float* gru_bhh = (const float*)d_in[12];
  const float* s2p_w1 = (const float*)d_in[13];
  const float* s2p_b1 = (const float*)d_in[14];
  const float* s2p_w2 = (const float*)d_in[15];
  const float* s2p_b2 = (const float*)d_in[16];
  const float* s2p_w3 = (const float*)d_in[17];
  const float* s2p_b3 = (const float*)d_in[18];
  const float* g2p_w1 = (const float*)d_in[19];
  const float* g2p_b1 = (const float*)d_in[20];
  const float* g2p_w2 = (const float*)d_in[21];
  const float* g2p_b2 = (const float*)d_in[22];
  const int* x_ids        = (const int*)d_in[23];
  const int* stemtype_ids = (const int*)d_in[24];
  const int* bond_ids     = (const int*)d_in[25];
  const int* edge_src     = (const int*)d_in[26];
  const int* edge_dst     = (const int*)d_in[27];
  const int* stems_local  = (const int*)d_in[30];

  float* wihT = (float*)d_ws;              // [128][384]
  float* whhT = wihT + 3*H*H;              // [128][384]
  float* stem_out = (float*)d_out;         // [4096][105]
  float* mol_out  = stem_out + 4096*OPS;

  transpose_k<<<192, 256, 0, stream>>>(gru_wih, gru_whh, wihT, whhT);
  graph_k<<<512, 256, 0, stream>>>(emb_block, emb_stem, emb_bond, conv_root, conv_bias,
      b2e_w1, b2e_b1, b2e_w2, b2e_b2, wihT, whhT, gru_bih, gru_bhh,
      s2p_w1, s2p_b1, s2p_w2, s2p_b2, s2p_w3, s2p_b3,
      g2p_w1, g2p_b1, g2p_w2, g2p_b2,
      x_ids, stemtype_ids, bond_ids, edge_src, edge_dst, stems_local,
      stem_out, mol_out);
}